// Round 1
// baseline (53.380 us; speedup 1.0000x reference)
//
#include <hip/hip_runtime.h>
#include <math.h>

#define BB 8
#define KK 4
#define CT 524288          // C*T = 2*262144
#define VECS (CT/4)        // float4 count per (b,k)
#define NBITS 2048         // 8*4*64
#define NACC 25            // 16 cross + 4 p2 + 4 t2 + 1 cons

__global__ __launch_bounds__(256) void floss_reduce(
    const float* __restrict__ sep, const float* __restrict__ src,
    const float* __restrict__ mix, float* __restrict__ ws) {
  const int b = blockIdx.y;
  const float4* sepb = (const float4*)(sep + (size_t)b * KK * CT);
  const float4* srcb = (const float4*)(src + (size_t)b * KK * CT);
  const float4* mixb = (const float4*)(mix + (size_t)b * CT);

  float cr[4][4] = {};
  float p2[4] = {};
  float t2[4] = {};
  float cons = 0.f;

  const int stride = gridDim.x * blockDim.x;
  for (int v = blockIdx.x * blockDim.x + threadIdx.x; v < VECS; v += stride) {
    float s[4][4], t[4][4], m[4];
    #pragma unroll
    for (int k = 0; k < 4; ++k) {
      float4 x = sepb[(size_t)k * VECS + v];
      s[k][0] = x.x; s[k][1] = x.y; s[k][2] = x.z; s[k][3] = x.w;
      float4 y = srcb[(size_t)k * VECS + v];
      t[k][0] = y.x; t[k][1] = y.y; t[k][2] = y.z; t[k][3] = y.w;
    }
    float4 mm = mixb[v];
    m[0] = mm.x; m[1] = mm.y; m[2] = mm.z; m[3] = mm.w;
    #pragma unroll
    for (int l = 0; l < 4; ++l) {
      #pragma unroll
      for (int i = 0; i < 4; ++i) {
        p2[i] += s[i][l] * s[i][l];
        t2[i] += t[i][l] * t[i][l];
        #pragma unroll
        for (int j = 0; j < 4; ++j) cr[i][j] += s[i][l] * t[j][l];
      }
      float sm = s[0][l] + s[1][l] + s[2][l] + s[3][l] - m[l];
      cons += sm * sm;
    }
  }

  float acc[NACC];
  #pragma unroll
  for (int i = 0; i < 4; ++i)
    #pragma unroll
    for (int j = 0; j < 4; ++j) acc[i * 4 + j] = cr[i][j];
  #pragma unroll
  for (int i = 0; i < 4; ++i) { acc[16 + i] = p2[i]; acc[20 + i] = t2[i]; }
  acc[24] = cons;

  // 64-lane wave reduce
  #pragma unroll
  for (int a = 0; a < NACC; ++a) {
    #pragma unroll
    for (int off = 32; off > 0; off >>= 1)
      acc[a] += __shfl_down(acc[a], off);
  }

  __shared__ float lds[4][NACC];
  const int wave = threadIdx.x >> 6, lane = threadIdx.x & 63;
  if (lane == 0) {
    #pragma unroll
    for (int a = 0; a < NACC; ++a) lds[wave][a] = acc[a];
  }
  __syncthreads();
  if (threadIdx.x < NACC) {
    float v = lds[0][threadIdx.x] + lds[1][threadIdx.x] +
              lds[2][threadIdx.x] + lds[3][threadIdx.x];
    float* dst = (threadIdx.x == 24) ? (ws + BB * 24)
                                     : (ws + b * 24 + threadIdx.x);
    atomicAdd(dst, v);
  }
}

__global__ __launch_bounds__(256) void floss_finalize(
    const float* __restrict__ ws, const float* __restrict__ pred_bits,
    const int* __restrict__ target_bits, const float* __restrict__ flow_loss,
    float* __restrict__ out) {
  // BCE over 2048 elements
  float acc = 0.f;
  for (int i = threadIdx.x; i < NBITS; i += 256) {
    float tb = (float)target_bits[i];
    float p = pred_bits[i];
    p = fminf(fmaxf(p, 1e-7f), 1.f - 1e-7f);
    acc += tb * logf(p) + (1.f - tb) * logf(1.f - p);
  }
  #pragma unroll
  for (int off = 32; off > 0; off >>= 1) acc += __shfl_down(acc, off);
  __shared__ float sacc[4];
  const int wave = threadIdx.x >> 6, lane = threadIdx.x & 63;
  if (lane == 0) sacc[wave] = acc;
  __syncthreads();

  if (threadIdx.x == 0) {
    float bsum = sacc[0] + sacc[1] + sacc[2] + sacc[3];
    float bce = -bsum / (float)NBITS;
    float bit = bce * 0.5f;

    // greedy PIT matching per batch (matches jnp argmin-first-tie semantics)
    const float inv_n = 1.f / (float)CT;
    float recon_sum = 0.f;
    for (int b = 0; b < BB; ++b) {
      const float* w = ws + b * 24;
      float cost[4][4];
      for (int i = 0; i < 4; ++i)
        for (int j = 0; j < 4; ++j)
          cost[i][j] = (w[16 + i] + w[20 + j] - 2.f * w[i * 4 + j]) * inv_n;
      bool used[4] = {false, false, false, false};
      for (int i = 0; i < 4; ++i) {
        int bj = 0; float bv = INFINITY;
        for (int j = 0; j < 4; ++j) {
          if (!used[j] && cost[i][j] < bv) { bv = cost[i][j]; bj = j; }
        }
        recon_sum += bv; used[bj] = true;
      }
    }
    float recon = recon_sum / (float)BB * 0.1f;
    float cons = ws[BB * 24] / (float)(BB * CT) * 0.1f;
    float flow = flow_loss[0];
    out[0] = flow;
    out[1] = recon;
    out[2] = cons;
    out[3] = bit;
    out[4] = flow + recon + cons + bit;
  }
}

extern "C" void kernel_launch(void* const* d_in, const int* in_sizes, int n_in,
                              void* d_out, int out_size, void* d_ws, size_t ws_size,
                              hipStream_t stream) {
  const float* sep       = (const float*)d_in[0];
  const float* src       = (const float*)d_in[1];
  const float* mix       = (const float*)d_in[2];
  const float* pred_bits = (const float*)d_in[3];
  const float* flow      = (const float*)d_in[4];
  const int*   tgt_bits  = (const int*)d_in[5];
  float* ws = (float*)d_ws;

  hipMemsetAsync(d_ws, 0, (BB * 24 + 1) * sizeof(float), stream);
  floss_reduce<<<dim3(128, BB), 256, 0, stream>>>(sep, src, mix, ws);
  floss_finalize<<<1, 256, 0, stream>>>(ws, pred_bits, tgt_bits, flow, (float*)d_out);
}

// Round 2
// 53.282 us; speedup vs baseline: 1.0018x; 1.0018x over previous
//
#include <hip/hip_runtime.h>
#include <math.h>

#define BB 8
#define KK 4
#define CT 524288          // C*T = 2*262144
#define VECS (CT/4)        // 131072 float4 per (b,k)
#define GX 128             // blocks per batch
#define TPB 256
#define PPT 4              // positions per thread: VECS/(GX*TPB)
#define NBITS 2048         // 8*4*64
#define NACC 25            // 16 cross + 4 p2 + 4 t2 + 1 cons

__global__ __launch_bounds__(256, 4) void floss_reduce(
    const float* __restrict__ sep, const float* __restrict__ src,
    const float* __restrict__ mix, float* __restrict__ ws) {
  const int b = blockIdx.y;
  const float4* sepb = (const float4*)(sep + (size_t)b * KK * CT);
  const float4* srcb = (const float4*)(src + (size_t)b * KK * CT);
  const float4* mixb = (const float4*)(mix + (size_t)b * CT);

  float cr[4][4] = {};
  float p2[4] = {};
  float t2[4] = {};
  float cons = 0.f;

  const int base = blockIdx.x * TPB + threadIdx.x;  // 0..32767
  #pragma unroll
  for (int p = 0; p < PPT; ++p) {
    const int v = base + p * (GX * TPB);
    float s[4][4], t[4][4], m[4];
    #pragma unroll
    for (int k = 0; k < 4; ++k) {
      float4 x = sepb[(size_t)k * VECS + v];
      s[k][0] = x.x; s[k][1] = x.y; s[k][2] = x.z; s[k][3] = x.w;
      float4 y = srcb[(size_t)k * VECS + v];
      t[k][0] = y.x; t[k][1] = y.y; t[k][2] = y.z; t[k][3] = y.w;
    }
    float4 mm = mixb[v];
    m[0] = mm.x; m[1] = mm.y; m[2] = mm.z; m[3] = mm.w;
    #pragma unroll
    for (int l = 0; l < 4; ++l) {
      #pragma unroll
      for (int i = 0; i < 4; ++i) {
        p2[i] += s[i][l] * s[i][l];
        t2[i] += t[i][l] * t[i][l];
        #pragma unroll
        for (int j = 0; j < 4; ++j) cr[i][j] += s[i][l] * t[j][l];
      }
      float sm = s[0][l] + s[1][l] + s[2][l] + s[3][l] - m[l];
      cons += sm * sm;
    }
  }

  float acc[NACC];
  #pragma unroll
  for (int i = 0; i < 4; ++i)
    #pragma unroll
    for (int j = 0; j < 4; ++j) acc[i * 4 + j] = cr[i][j];
  #pragma unroll
  for (int i = 0; i < 4; ++i) { acc[16 + i] = p2[i]; acc[20 + i] = t2[i]; }
  acc[24] = cons;

  // 64-lane wave reduce
  #pragma unroll
  for (int a = 0; a < NACC; ++a) {
    #pragma unroll
    for (int off = 32; off > 0; off >>= 1)
      acc[a] += __shfl_down(acc[a], off);
  }

  __shared__ float lds[4][NACC];
  const int wave = threadIdx.x >> 6, lane = threadIdx.x & 63;
  if (lane == 0) {
    #pragma unroll
    for (int a = 0; a < NACC; ++a) lds[wave][a] = acc[a];
  }
  __syncthreads();
  if (threadIdx.x < NACC) {
    float v = lds[0][threadIdx.x] + lds[1][threadIdx.x] +
              lds[2][threadIdx.x] + lds[3][threadIdx.x];
    // non-atomic per-block partial: ws[(b*GX + bx)*NACC + a]
    ws[((size_t)b * GX + blockIdx.x) * NACC + threadIdx.x] = v;
  }
}

__global__ __launch_bounds__(256) void floss_finalize(
    const float* __restrict__ ws, const float* __restrict__ pred_bits,
    const int* __restrict__ target_bits, const float* __restrict__ flow_loss,
    float* __restrict__ out) {
  __shared__ float sums[BB * NACC];
  const int t = threadIdx.x;

  // reduce the 1024 per-block partials -> per-batch sums
  if (t < BB * NACC) {
    const int b = t / NACC, a = t % NACC;
    const float* p = ws + (size_t)b * GX * NACC + a;
    float s = 0.f;
    #pragma unroll 8
    for (int g = 0; g < GX; ++g) s += p[(size_t)g * NACC];
    sums[t] = s;
  }

  // BCE over 2048 elements
  float acc = 0.f;
  for (int i = t; i < NBITS; i += 256) {
    float tb = (float)target_bits[i];
    float p = pred_bits[i];
    p = fminf(fmaxf(p, 1e-7f), 1.f - 1e-7f);
    acc += tb * logf(p) + (1.f - tb) * logf(1.f - p);
  }
  #pragma unroll
  for (int off = 32; off > 0; off >>= 1) acc += __shfl_down(acc, off);
  __shared__ float sacc[4];
  const int wave = t >> 6, lane = t & 63;
  if (lane == 0) sacc[wave] = acc;
  __syncthreads();

  if (t == 0) {
    float bsum = sacc[0] + sacc[1] + sacc[2] + sacc[3];
    float bce = -bsum / (float)NBITS;
    float bit = bce * 0.5f;

    // greedy PIT matching per batch
    const float inv_n = 1.f / (float)CT;
    float recon_sum = 0.f;
    float cons_sum = 0.f;
    for (int b = 0; b < BB; ++b) {
      const float* w = sums + b * NACC;
      cons_sum += w[24];
      float cost[4][4];
      for (int i = 0; i < 4; ++i)
        for (int j = 0; j < 4; ++j)
          cost[i][j] = (w[16 + i] + w[20 + j] - 2.f * w[i * 4 + j]) * inv_n;
      bool used[4] = {false, false, false, false};
      for (int i = 0; i < 4; ++i) {
        int bj = 0; float bv = INFINITY;
        for (int j = 0; j < 4; ++j) {
          if (!used[j] && cost[i][j] < bv) { bv = cost[i][j]; bj = j; }
        }
        recon_sum += bv; used[bj] = true;
      }
    }
    float recon = recon_sum / (float)BB * 0.1f;
    float cons = cons_sum / (float)(BB * CT) * 0.1f;
    float flow = flow_loss[0];
    out[0] = flow;
    out[1] = recon;
    out[2] = cons;
    out[3] = bit;
    out[4] = flow + recon + cons + bit;
  }
}

extern "C" void kernel_launch(void* const* d_in, const int* in_sizes, int n_in,
                              void* d_out, int out_size, void* d_ws, size_t ws_size,
                              hipStream_t stream) {
  const float* sep       = (const float*)d_in[0];
  const float* src       = (const float*)d_in[1];
  const float* mix       = (const float*)d_in[2];
  const float* pred_bits = (const float*)d_in[3];
  const float* flow      = (const float*)d_in[4];
  const int*   tgt_bits  = (const int*)d_in[5];
  float* ws = (float*)d_ws;

  floss_reduce<<<dim3(GX, BB), TPB, 0, stream>>>(sep, src, mix, ws);
  floss_finalize<<<1, TPB, 0, stream>>>(ws, pred_bits, tgt_bits, flow, (float*)d_out);
}

// Round 3
// 47.450 us; speedup vs baseline: 1.1250x; 1.1229x over previous
//
#include <hip/hip_runtime.h>
#include <math.h>

#define BB 8
#define KK 4
#define CT 524288          // C*T = 2*262144
#define VECS (CT/4)        // 131072 float4 per (b,k)
#define GX 256             // blocks per batch
#define TPB 256
#define NBITS 2048         // 8*4*64
#define NACC 25            // 16 cross + 4 p2 + 4 t2 + 1 cons

__global__ __launch_bounds__(256, 4) void floss_reduce(
    const float* __restrict__ sep, const float* __restrict__ src,
    const float* __restrict__ mix, float* __restrict__ ws) {
  const int b = blockIdx.y;
  const float4* sepb = (const float4*)(sep + (size_t)b * KK * CT);
  const float4* srcb = (const float4*)(src + (size_t)b * KK * CT);
  const float4* mixb = (const float4*)(mix + (size_t)b * CT);

  // two positions per thread; both loads for all 9 streams issued up front
  const int v0 = blockIdx.x * (2 * TPB) + threadIdx.x;
  const int v1 = v0 + TPB;

  float4 S0[4], T0[4], S1[4], T1[4], M0, M1;
  #pragma unroll
  for (int k = 0; k < 4; ++k) S0[k] = sepb[(size_t)k * VECS + v0];
  #pragma unroll
  for (int k = 0; k < 4; ++k) T0[k] = srcb[(size_t)k * VECS + v0];
  M0 = mixb[v0];
  #pragma unroll
  for (int k = 0; k < 4; ++k) S1[k] = sepb[(size_t)k * VECS + v1];
  #pragma unroll
  for (int k = 0; k < 4; ++k) T1[k] = srcb[(size_t)k * VECS + v1];
  M1 = mixb[v1];

  float cr[4][4] = {};
  float p2[4] = {};
  float t2[4] = {};
  float cons = 0.f;

  // consume position set 0 then 1 (loads already all in flight)
  #pragma unroll
  for (int h = 0; h < 2; ++h) {
    const float4* S = h ? S1 : S0;
    const float4* T = h ? T1 : T0;
    const float4  M = h ? M1 : M0;
    float s[4][4], t[4][4], m[4];
    #pragma unroll
    for (int k = 0; k < 4; ++k) {
      s[k][0] = S[k].x; s[k][1] = S[k].y; s[k][2] = S[k].z; s[k][3] = S[k].w;
      t[k][0] = T[k].x; t[k][1] = T[k].y; t[k][2] = T[k].z; t[k][3] = T[k].w;
    }
    m[0] = M.x; m[1] = M.y; m[2] = M.z; m[3] = M.w;
    #pragma unroll
    for (int l = 0; l < 4; ++l) {
      #pragma unroll
      for (int i = 0; i < 4; ++i) {
        p2[i] += s[i][l] * s[i][l];
        t2[i] += t[i][l] * t[i][l];
        #pragma unroll
        for (int j = 0; j < 4; ++j) cr[i][j] += s[i][l] * t[j][l];
      }
      float sm = s[0][l] + s[1][l] + s[2][l] + s[3][l] - m[l];
      cons += sm * sm;
    }
  }

  float acc[NACC];
  #pragma unroll
  for (int i = 0; i < 4; ++i)
    #pragma unroll
    for (int j = 0; j < 4; ++j) acc[i * 4 + j] = cr[i][j];
  #pragma unroll
  for (int i = 0; i < 4; ++i) { acc[16 + i] = p2[i]; acc[20 + i] = t2[i]; }
  acc[24] = cons;

  // 64-lane wave reduce
  #pragma unroll
  for (int a = 0; a < NACC; ++a) {
    #pragma unroll
    for (int off = 32; off > 0; off >>= 1)
      acc[a] += __shfl_down(acc[a], off);
  }

  __shared__ float lds[4][NACC];
  const int wave = threadIdx.x >> 6, lane = threadIdx.x & 63;
  if (lane == 0) {
    #pragma unroll
    for (int a = 0; a < NACC; ++a) lds[wave][a] = acc[a];
  }
  __syncthreads();
  if (threadIdx.x < NACC) {
    float v = lds[0][threadIdx.x] + lds[1][threadIdx.x] +
              lds[2][threadIdx.x] + lds[3][threadIdx.x];
    // transposed layout: ws[(a*BB + b)*GX + gx] so finalize reads contiguously
    ws[((size_t)threadIdx.x * BB + b) * GX + blockIdx.x] = v;
  }
}

__global__ __launch_bounds__(256) void floss_finalize(
    const float* __restrict__ ws, const float* __restrict__ pred_bits,
    const int* __restrict__ target_bits, const float* __restrict__ flow_loss,
    float* __restrict__ out) {
  __shared__ float sums[BB * NACC];
  const int t = threadIdx.x;

  // reduce the GX per-block partials -> per-(a,b) sums; contiguous float4 reads
  if (t < BB * NACC) {
    const int a = t >> 3, b = t & 7;           // t = a*8 + b
    const float4* p = (const float4*)(ws + ((size_t)a * BB + b) * GX);
    float4 s4 = make_float4(0.f, 0.f, 0.f, 0.f);
    #pragma unroll 8
    for (int g = 0; g < GX / 4; ++g) {
      float4 x = p[g];
      s4.x += x.x; s4.y += x.y; s4.z += x.z; s4.w += x.w;
    }
    sums[b * NACC + a] = s4.x + s4.y + s4.z + s4.w;
  }

  // BCE over 2048 elements
  float acc = 0.f;
  for (int i = t; i < NBITS; i += 256) {
    float tb = (float)target_bits[i];
    float p = pred_bits[i];
    p = fminf(fmaxf(p, 1e-7f), 1.f - 1e-7f);
    acc += tb * logf(p) + (1.f - tb) * logf(1.f - p);
  }
  #pragma unroll
  for (int off = 32; off > 0; off >>= 1) acc += __shfl_down(acc, off);
  __shared__ float sacc[4];
  const int wave = t >> 6, lane = t & 63;
  if (lane == 0) sacc[wave] = acc;
  __syncthreads();

  if (t == 0) {
    float bsum = sacc[0] + sacc[1] + sacc[2] + sacc[3];
    float bce = -bsum / (float)NBITS;
    float bit = bce * 0.5f;

    // greedy PIT matching per batch
    const float inv_n = 1.f / (float)CT;
    float recon_sum = 0.f;
    float cons_sum = 0.f;
    for (int b = 0; b < BB; ++b) {
      const float* w = sums + b * NACC;
      cons_sum += w[24];
      float cost[4][4];
      for (int i = 0; i < 4; ++i)
        for (int j = 0; j < 4; ++j)
          cost[i][j] = (w[16 + i] + w[20 + j] - 2.f * w[i * 4 + j]) * inv_n;
      bool used[4] = {false, false, false, false};
      for (int i = 0; i < 4; ++i) {
        int bj = 0; float bv = INFINITY;
        for (int j = 0; j < 4; ++j) {
          if (!used[j] && cost[i][j] < bv) { bv = cost[i][j]; bj = j; }
        }
        recon_sum += bv; used[bj] = true;
      }
    }
    float recon = recon_sum / (float)BB * 0.1f;
    float cons = cons_sum / (float)(BB * CT) * 0.1f;
    float flow = flow_loss[0];
    out[0] = flow;
    out[1] = recon;
    out[2] = cons;
    out[3] = bit;
    out[4] = flow + recon + cons + bit;
  }
}

extern "C" void kernel_launch(void* const* d_in, const int* in_sizes, int n_in,
                              void* d_out, int out_size, void* d_ws, size_t ws_size,
                              hipStream_t stream) {
  const float* sep       = (const float*)d_in[0];
  const float* src       = (const float*)d_in[1];
  const float* mix       = (const float*)d_in[2];
  const float* pred_bits = (const float*)d_in[3];
  const float* flow      = (const float*)d_in[4];
  const int*   tgt_bits  = (const int*)d_in[5];
  float* ws = (float*)d_ws;

  floss_reduce<<<dim3(GX, BB), TPB, 0, stream>>>(sep, src, mix, ws);
  floss_finalize<<<1, TPB, 0, stream>>>(ws, pred_bits, tgt_bits, flow, (float*)d_out);
}

// Round 4
// 41.980 us; speedup vs baseline: 1.2716x; 1.1303x over previous
//
#include <hip/hip_runtime.h>
#include <math.h>

#define BB 8
#define KK 4
#define CT 524288          // C*T
#define VECS (CT/4)        // 131072 float4 per (b,k)
#define GX 64              // blocks per batch
#define TPB 256
#define NWAVE 4
#define NIT 8              // VECS / (GX*NWAVE*64)
#define NBITS 2048
#define NACC 25            // 16 cross + 4 p2 + 4 t2 + 1 cons
#define SLOT 256           // floats per stream slot (64 lanes * 4)
#define BUF (9*SLOT)       // floats per buffer (9 streams)

typedef __attribute__((address_space(1))) const void GV;
typedef __attribute__((address_space(3))) void LV;

__device__ __forceinline__ void gl_lds16(const void* g, void* l) {
  __builtin_amdgcn_global_load_lds((GV*)g, (LV*)l, 16, 0, 0);
}

__global__ __launch_bounds__(TPB, 2) void floss_reduce(
    const float* __restrict__ sep, const float* __restrict__ src,
    const float* __restrict__ mix, float* __restrict__ ws) {
  __shared__ float smem[NWAVE * 2 * BUF];   // 72 KB staging
  __shared__ float redu[NWAVE][NACC];

  const int b = blockIdx.y;
  const int wave = threadIdx.x >> 6, lane = threadIdx.x & 63;

  const float4* sepv = (const float4*)(sep + (size_t)b * KK * CT);
  const float4* srcv = (const float4*)(src + (size_t)b * KK * CT);
  const float4* mixv = (const float4*)(mix + (size_t)b * CT);

  // this wave's contiguous run of float4 positions
  const int wbase = (blockIdx.x * NWAVE + wave) * (NIT * 64);
  float* wsm = smem + wave * (2 * BUF);

  float cr[4][4] = {};
  float p2[4] = {};
  float t2[4] = {};
  float cons = 0.f;

  // issue all 9 stream loads for iteration `it` into buffer (it&1)
  auto issue = [&](int it) {
    float* dst = wsm + (it & 1) * BUF;
    const int v = wbase + it * 64 + lane;      // per-lane global float4 index
    #pragma unroll
    for (int k = 0; k < 4; ++k)
      gl_lds16(sepv + (size_t)k * VECS + v, dst + k * SLOT);
    #pragma unroll
    for (int k = 0; k < 4; ++k)
      gl_lds16(srcv + (size_t)k * VECS + v, dst + (4 + k) * SLOT);
    gl_lds16(mixv + v, dst + 8 * SLOT);
  };

  issue(0);
  #pragma unroll
  for (int it = 0; it < NIT; ++it) {
    if (it + 1 < NIT) issue(it + 1);           // keep next buffer in flight
    __builtin_amdgcn_sched_barrier(0);
    if (it + 1 < NIT)
      __builtin_amdgcn_s_waitcnt(0x0F79);      // vmcnt(9): oldest 9 (cur buf) done
    else
      __builtin_amdgcn_s_waitcnt(0x0F70);      // vmcnt(0): final drain
    __builtin_amdgcn_sched_barrier(0);

    const float4* buf = (const float4*)(wsm + (it & 1) * BUF);
    float4 S[4], T[4], M;
    #pragma unroll
    for (int k = 0; k < 4; ++k) S[k] = buf[k * 64 + lane];
    #pragma unroll
    for (int k = 0; k < 4; ++k) T[k] = buf[(4 + k) * 64 + lane];
    M = buf[8 * 64 + lane];

    float s[4][4], t[4][4], m[4];
    #pragma unroll
    for (int k = 0; k < 4; ++k) {
      s[k][0] = S[k].x; s[k][1] = S[k].y; s[k][2] = S[k].z; s[k][3] = S[k].w;
      t[k][0] = T[k].x; t[k][1] = T[k].y; t[k][2] = T[k].z; t[k][3] = T[k].w;
    }
    m[0] = M.x; m[1] = M.y; m[2] = M.z; m[3] = M.w;
    #pragma unroll
    for (int l = 0; l < 4; ++l) {
      #pragma unroll
      for (int i = 0; i < 4; ++i) {
        p2[i] += s[i][l] * s[i][l];
        t2[i] += t[i][l] * t[i][l];
        #pragma unroll
        for (int j = 0; j < 4; ++j) cr[i][j] += s[i][l] * t[j][l];
      }
      float sm = s[0][l] + s[1][l] + s[2][l] + s[3][l] - m[l];
      cons += sm * sm;
    }
    __builtin_amdgcn_sched_barrier(0);
  }

  float acc[NACC];
  #pragma unroll
  for (int i = 0; i < 4; ++i)
    #pragma unroll
    for (int j = 0; j < 4; ++j) acc[i * 4 + j] = cr[i][j];
  #pragma unroll
  for (int i = 0; i < 4; ++i) { acc[16 + i] = p2[i]; acc[20 + i] = t2[i]; }
  acc[24] = cons;

  // 64-lane wave reduce
  #pragma unroll
  for (int a = 0; a < NACC; ++a) {
    #pragma unroll
    for (int off = 32; off > 0; off >>= 1)
      acc[a] += __shfl_down(acc[a], off);
  }
  if (lane == 0) {
    #pragma unroll
    for (int a = 0; a < NACC; ++a) redu[wave][a] = acc[a];
  }
  __syncthreads();
  if (threadIdx.x < NACC) {
    float v = redu[0][threadIdx.x] + redu[1][threadIdx.x] +
              redu[2][threadIdx.x] + redu[3][threadIdx.x];
    // transposed: ws[(a*BB + b)*GX + gx] -> contiguous reads in finalize
    ws[((size_t)threadIdx.x * BB + b) * GX + blockIdx.x] = v;
  }
}

__global__ __launch_bounds__(256) void floss_finalize(
    const float* __restrict__ ws, const float* __restrict__ pred_bits,
    const int* __restrict__ target_bits, const float* __restrict__ flow_loss,
    float* __restrict__ out) {
  __shared__ float sums[BB * NACC];
  const int t = threadIdx.x;

  if (t < BB * NACC) {
    const int a = t >> 3, b = t & 7;
    const float4* p = (const float4*)(ws + ((size_t)a * BB + b) * GX);
    float4 s4 = make_float4(0.f, 0.f, 0.f, 0.f);
    #pragma unroll
    for (int g = 0; g < GX / 4; ++g) {
      float4 x = p[g];
      s4.x += x.x; s4.y += x.y; s4.z += x.z; s4.w += x.w;
    }
    sums[b * NACC + a] = s4.x + s4.y + s4.z + s4.w;
  }

  float acc = 0.f;
  for (int i = t; i < NBITS; i += 256) {
    float tb = (float)target_bits[i];
    float p = pred_bits[i];
    p = fminf(fmaxf(p, 1e-7f), 1.f - 1e-7f);
    acc += tb * logf(p) + (1.f - tb) * logf(1.f - p);
  }
  #pragma unroll
  for (int off = 32; off > 0; off >>= 1) acc += __shfl_down(acc, off);
  __shared__ float sacc[4];
  const int wave = t >> 6, lane = t & 63;
  if (lane == 0) sacc[wave] = acc;
  __syncthreads();

  if (t == 0) {
    float bsum = sacc[0] + sacc[1] + sacc[2] + sacc[3];
    float bce = -bsum / (float)NBITS;
    float bit = bce * 0.5f;

    const float inv_n = 1.f / (float)CT;
    float recon_sum = 0.f;
    float cons_sum = 0.f;
    for (int b = 0; b < BB; ++b) {
      const float* w = sums + b * NACC;
      cons_sum += w[24];
      float cost[4][4];
      for (int i = 0; i < 4; ++i)
        for (int j = 0; j < 4; ++j)
          cost[i][j] = (w[16 + i] + w[20 + j] - 2.f * w[i * 4 + j]) * inv_n;
      bool used[4] = {false, false, false, false};
      for (int i = 0; i < 4; ++i) {
        int bj = 0; float bv = INFINITY;
        for (int j = 0; j < 4; ++j) {
          if (!used[j] && cost[i][j] < bv) { bv = cost[i][j]; bj = j; }
        }
        recon_sum += bv; used[bj] = true;
      }
    }
    float recon = recon_sum / (float)BB * 0.1f;
    float cons = cons_sum / (float)(BB * CT) * 0.1f;
    float flow = flow_loss[0];
    out[0] = flow;
    out[1] = recon;
    out[2] = cons;
    out[3] = bit;
    out[4] = flow + recon + cons + bit;
  }
}

extern "C" void kernel_launch(void* const* d_in, const int* in_sizes, int n_in,
                              void* d_out, int out_size, void* d_ws, size_t ws_size,
                              hipStream_t stream) {
  const float* sep       = (const float*)d_in[0];
  const float* src       = (const float*)d_in[1];
  const float* mix       = (const float*)d_in[2];
  const float* pred_bits = (const float*)d_in[3];
  const float* flow      = (const float*)d_in[4];
  const int*   tgt_bits  = (const int*)d_in[5];
  float* ws = (float*)d_ws;

  floss_reduce<<<dim3(GX, BB), TPB, 0, stream>>>(sep, src, mix, ws);
  floss_finalize<<<1, TPB, 0, stream>>>(ws, pred_bits, tgt_bits, flow, (float*)d_out);
}